// Round 3
// baseline (227.296 us; speedup 1.0000x reference)
//
#include <hip/hip_runtime.h>
#include <hip/hip_bf16.h>

// EdgeEmbedder fused kernel for MI355X (gfx950). Round 3.
//   R2 post-mortem: edge_main <78us (out of top-5), all four resources (MFMA 12,
//   HBM 24, L2 17, LDS 19-23 us) balanced -> concurrency-bound. This round:
//   operand-swapped MFMA (W as A-operand -> lane holds 4 consecutive out-cols,
//   direct float4 stores, no Cf transpose), XOR-swizzled 32KB LDS union ->
//   5 blocks/CU, barriers 5 -> 3.

typedef __attribute__((ext_vector_type(8))) short v8s;   // 8 x bf16 fragment
typedef __attribute__((ext_vector_type(4))) float v4f;   // 4 x f32 accumulator

#define PI_F 3.14159265358979323846f

__device__ __forceinline__ unsigned short f2bu(float x) {
    __hip_bfloat16 h = __float2bfloat16(x);
    return *reinterpret_cast<unsigned short*>(&h);
}

// ---------------------------------------------------------------------------
// Precompute (unchanged from R2): blocks 0..63 -> p rows; 64..319 -> relpos
// rows; 320..343 -> W1/W2 bf16 cast. All global reads coalesced.
// ---------------------------------------------------------------------------
__global__ __launch_bounds__(256) void precompute_kernel(
    const float* __restrict__ s, const float* __restrict__ W_sp,
    const float* __restrict__ b_sp, const float* __restrict__ W_rp,
    const float* __restrict__ b_rp, const float* __restrict__ W1,
    const float* __restrict__ W2,
    __hip_bfloat16* __restrict__ p_bf, __hip_bfloat16* __restrict__ relT,
    __hip_bfloat16* __restrict__ W1b, __hip_bfloat16* __restrict__ W2b)
{
    const int b = blockIdx.x;
    const int tid = threadIdx.x;
    __shared__ float lds[128 * 65 + 8 * 256];

    if (b < 64) {
        float* Wt   = lds;               // [128][65] transposed slice of W_sp
        float* srow = lds + 128 * 65;    // [8][256]
        const int row0 = b * 8;
        const int f  = tid & 63;
        const int rh = tid >> 6;
        #pragma unroll
        for (int k = 0; k < 8; k++) {
            const int idx = tid + 256 * k;
            const int r = idx >> 8, d = idx & 255;
            srow[r * 256 + d] = s[(row0 + r) * 256 + d];
        }
        float acc0 = b_sp[f];
        float acc1 = acc0;
        for (int pass = 0; pass < 2; pass++) {
            __syncthreads();
            #pragma unroll
            for (int k = 0; k < 32; k++) {
                const int idx = tid + 256 * k;
                const int fs = idx >> 7, ds = idx & 127;
                Wt[ds * 65 + fs] = W_sp[fs * 256 + pass * 128 + ds];
            }
            __syncthreads();
            #pragma unroll 4
            for (int d = 0; d < 128; d++) {
                const float w = Wt[d * 65 + f];
                acc0 += srow[rh * 256 + pass * 128 + d] * w;
                acc1 += srow[(rh + 4) * 256 + pass * 128 + d] * w;
            }
        }
        p_bf[(row0 + rh) * 64 + f]     = __float2bfloat16(acc0);
        p_bf[(row0 + rh + 4) * 64 + f] = __float2bfloat16(acc1);
    } else if (b < 320) {
        float* WrT  = lds;               // [64][65] transposed W_rp
        float* femb = lds + 64 * 65;     // [4][64]
        const int r0 = (b - 64) * 4;
        #pragma unroll
        for (int k = 0; k < 16; k++) {
            const int idx = tid + 256 * k;
            const int g = idx >> 6, ff = idx & 63;
            WrT[ff * 65 + g] = W_rp[g * 64 + ff];
        }
        {
            const int r = tid >> 6, c = tid & 63;
            const float rel = (float)(r0 + r - 511);
            const int K = c & 31;
            const float freq = powf(2056.0f, (2.0f * (float)K) / 64.0f);
            const float ang = rel * PI_F / freq;
            femb[r * 64 + c] = (c < 32) ? sinf(ang) : cosf(ang);
        }
        __syncthreads();
        const int g = tid & 63, r = tid >> 6;
        float acc = b_rp[g];
        #pragma unroll
        for (int ff = 0; ff < 64; ff++) acc += femb[r * 64 + ff] * WrT[ff * 65 + g];
        relT[(r0 + r) * 64 + g] = __float2bfloat16(acc);
    } else {
        #pragma unroll
        for (int k = 0; k < 2; k++) {
            const int idx4 = (b - 320) * 512 + k * 256 + tid;
            const int e = idx4 * 4;
            const float4 v = (e < 32768) ? *(const float4*)&W1[e]
                                         : *(const float4*)&W2[e - 32768];
            __hip_bfloat16* dst = (e < 32768) ? (W1b + e) : (W2b + (e - 32768));
            dst[0] = __float2bfloat16(v.x);
            dst[1] = __float2bfloat16(v.y);
            dst[2] = __float2bfloat16(v.z);
            dst[3] = __float2bfloat16(v.w);
        }
    }
}

// ---------------------------------------------------------------------------
// Main fused kernel. Block = 64 pairs (one i, 64 consecutive j), 256 threads.
// Wave wv owns output cols [32wv, 32wv+32) for all 64 rows.
// MFMA operands SWAPPED: A = weight frag (m = out col), B = tile frag
// (n = tile row). D layout: out-col = quad*4+reg (4 consecutive cols per lane
// -> float4 stores), tile-row = l16.
// LDS: single 32768B region, XOR-swizzled (chunk16B ^ (row&7)):
//   phase 1: all_edge tile, 64 rows x 512B;  phase 2 (overlay): H, 64 x 256B.
// ---------------------------------------------------------------------------
__global__ __launch_bounds__(256, 5) void edge_main(
    const float* __restrict__ t3, const float* __restrict__ sc3,
    const float* __restrict__ pre,
    const float* __restrict__ b1, const float* __restrict__ b2,
    const __hip_bfloat16* __restrict__ p_bf, const __hip_bfloat16* __restrict__ relT,
    const __hip_bfloat16* __restrict__ W1b, const __hip_bfloat16* __restrict__ W2b,
    float* __restrict__ out)
{
    __shared__ char smem[32768];

    const int tid = threadIdx.x;
    const int blk = blockIdx.x;
    const int i  = blk >> 3;
    const int j0 = (blk & 7) << 6;

    const int wv   = tid >> 6;
    const int lane = tid & 63;
    const int l16  = lane & 15;
    const int quad = lane >> 4;
    const int cbase = wv * 32;                 // this wave's output-col base

    // early issue: biases (4 consecutive cols per lane) + kt0 W1 frags
    const float4 b1v0 = *(const float4*)&b1[cbase + quad * 4];
    const float4 b1v1 = *(const float4*)&b1[cbase + 16 + quad * 4];
    const float4 b2v0 = *(const float4*)&b2[cbase + quad * 4];
    const float4 b2v1 = *(const float4*)&b2[cbase + 16 + quad * 4];
    const __hip_bfloat16* w1m0 = W1b + (cbase + l16) * 256 + quad * 8;
    const __hip_bfloat16* w1m1 = w1m0 + 16 * 256;
    const __hip_bfloat16* w2m0 = W2b + (cbase + l16) * 128 + quad * 8;
    const __hip_bfloat16* w2m1 = w2m0 + 16 * 128;
    const v8s p10 = *(const v8s*)w1m0;
    const v8s p11 = *(const v8s*)w1m1;

    // ---- build all_edge tile (XOR-swizzled rows of 512B) ----
    // segments: [0,64) p_i  [64,128) p_j  [128,192) relpos  [192,236) RBF  [236,256) pre
    #pragma unroll
    for (int c = tid; c < 512; c += 256) {
        const int r  = c >> 3;
        const int ck = c & 7;                  // logical 16B chunk within group
        const int px = (ck ^ (r & 7)) << 4;    // swizzled byte offset in group
        char* rowp = smem + r * 512;
        *(uint4*)(rowp + px)       = *(const uint4*)&p_bf[i * 64 + ck * 8];
        *(uint4*)(rowp + 128 + px) = *(const uint4*)&p_bf[(j0 + r) * 64 + ck * 8];
        *(uint4*)(rowp + 256 + px) = *(const uint4*)&relT[(i - (j0 + r) + 511) * 64 + ck * 8];
    }
    for (int c = tid; c < 320; c += 256) {     // pair_repr_pre: 20 f32/row
        const int r = c / 5;
        const int q = c % 5;
        const int col = 236 + q * 4;
        const float4 v = *(const float4*)&pre[((size_t)i * 512 + j0 + r) * 20 + q * 4];
        union { unsigned short s4[4]; uint2 u; } pk;
        pk.s4[0] = f2bu(v.x); pk.s4[1] = f2bu(v.y);
        pk.s4[2] = f2bu(v.z); pk.s4[3] = f2bu(v.w);
        const int off = r * 512 + (((col >> 3) ^ (r & 7)) << 4) + ((col & 7) * 2);
        *(uint2*)(smem + off) = pk.u;
    }
    {   // RBF: 4 threads/row x 11 features, distances in-register
        const int r  = tid >> 2;
        const int fo = (tid & 3) * 11;
        const int j = j0 + r;
        const float dxt = t3[i * 3 + 0] - t3[j * 3 + 0];
        const float dyt = t3[i * 3 + 1] - t3[j * 3 + 1];
        const float dzt = t3[i * 3 + 2] - t3[j * 3 + 2];
        const float dt = sqrtf(dxt * dxt + dyt * dyt + dzt * dzt);
        const float dxs = sc3[i * 3 + 0] - sc3[j * 3 + 0];
        const float dys = sc3[i * 3 + 1] - sc3[j * 3 + 1];
        const float dzs = sc3[i * 3 + 2] - sc3[j * 3 + 2];
        const float ds = sqrtf(dxs * dxs + dys * dys + dzs * dzs);
        char* rowp = smem + r * 512;
        const int rx = r & 7;
        #pragma unroll
        for (int q = 0; q < 11; q++) {
            const int f = fo + q;
            const float d = (f < 22) ? dt : ds;
            const int m = (f < 22) ? f : f - 22;
            const float x = (d - (float)m * (20.0f / 21.0f)) * 1.1f;
            const int col = 192 + f;
            const int off = (((col >> 3) ^ rx) << 4) + ((col & 7) * 2);
            *(unsigned short*)(rowp + off) = f2bu(__expf(-x * x));
        }
    }
    __syncthreads();

    // ---- Layer 1: mfma(A=W1 frag, B=tile frag) over K=256 ----
    const int xorv = (l16 & 7) << 4;           // byte-level chunk XOR
    v4f acc[2][4];
    #pragma unroll
    for (int mt = 0; mt < 2; mt++)
        #pragma unroll
        for (int nt = 0; nt < 4; nt++) acc[mt][nt] = (v4f){0.f, 0.f, 0.f, 0.f};

    #pragma unroll
    for (int kt = 0; kt < 8; kt++) {
        const int po = ((kt * 4 + quad) * 16) ^ xorv;
        const v8s t0 = *(const v8s*)(smem + (l16     ) * 512 + po);
        const v8s t1 = *(const v8s*)(smem + (l16 + 16) * 512 + po);
        const v8s t2 = *(const v8s*)(smem + (l16 + 32) * 512 + po);
        const v8s t3f = *(const v8s*)(smem + (l16 + 48) * 512 + po);
        const v8s w0 = (kt == 0) ? p10 : *(const v8s*)(w1m0 + kt * 32);
        const v8s w1f = (kt == 0) ? p11 : *(const v8s*)(w1m1 + kt * 32);
        acc[0][0] = __builtin_amdgcn_mfma_f32_16x16x32_bf16(w0, t0,  acc[0][0], 0, 0, 0);
        acc[0][1] = __builtin_amdgcn_mfma_f32_16x16x32_bf16(w0, t1,  acc[0][1], 0, 0, 0);
        acc[0][2] = __builtin_amdgcn_mfma_f32_16x16x32_bf16(w0, t2,  acc[0][2], 0, 0, 0);
        acc[0][3] = __builtin_amdgcn_mfma_f32_16x16x32_bf16(w0, t3f, acc[0][3], 0, 0, 0);
        acc[1][0] = __builtin_amdgcn_mfma_f32_16x16x32_bf16(w1f, t0,  acc[1][0], 0, 0, 0);
        acc[1][1] = __builtin_amdgcn_mfma_f32_16x16x32_bf16(w1f, t1,  acc[1][1], 0, 0, 0);
        acc[1][2] = __builtin_amdgcn_mfma_f32_16x16x32_bf16(w1f, t2,  acc[1][2], 0, 0, 0);
        acc[1][3] = __builtin_amdgcn_mfma_f32_16x16x32_bf16(w1f, t3f, acc[1][3], 0, 0, 0);
    }
    __syncthreads();   // all tile reads done before H overlay

    // ---- H = relu(acc + b1) -> LDS (rows of 256B, swizzled), ushort4 ----
    #pragma unroll
    for (int mt = 0; mt < 2; mt++) {
        const float4 bv = mt ? b1v1 : b1v0;
        const int col = cbase + mt * 16 + quad * 4;
        #pragma unroll
        for (int nt = 0; nt < 4; nt++) {
            const int row = nt * 16 + l16;
            union { unsigned short s4[4]; uint2 u; } pk;
            pk.s4[0] = f2bu(fmaxf(acc[mt][nt][0] + bv.x, 0.f));
            pk.s4[1] = f2bu(fmaxf(acc[mt][nt][1] + bv.y, 0.f));
            pk.s4[2] = f2bu(fmaxf(acc[mt][nt][2] + bv.z, 0.f));
            pk.s4[3] = f2bu(fmaxf(acc[mt][nt][3] + bv.w, 0.f));
            const int off = row * 256 + (((col >> 3) ^ (row & 7)) << 4) + ((col & 7) * 2);
            *(uint2*)(smem + off) = pk.u;
        }
    }
    __syncthreads();

    // ---- Layer 2: mfma(A=W2 frag, B=H frag) over K=128 ----
    v4f acc2[2][4];
    #pragma unroll
    for (int mt = 0; mt < 2; mt++)
        #pragma unroll
        for (int nt = 0; nt < 4; nt++) acc2[mt][nt] = (v4f){0.f, 0.f, 0.f, 0.f};

    #pragma unroll
    for (int kt = 0; kt < 4; kt++) {
        const int po = ((kt * 4 + quad) * 16) ^ xorv;
        const v8s t0 = *(const v8s*)(smem + (l16     ) * 256 + po);
        const v8s t1 = *(const v8s*)(smem + (l16 + 16) * 256 + po);
        const v8s t2 = *(const v8s*)(smem + (l16 + 32) * 256 + po);
        const v8s t3f = *(const v8s*)(smem + (l16 + 48) * 256 + po);
        const v8s w0 = *(const v8s*)(w2m0 + kt * 32);
        const v8s w1f = *(const v8s*)(w2m1 + kt * 32);
        acc2[0][0] = __builtin_amdgcn_mfma_f32_16x16x32_bf16(w0, t0,  acc2[0][0], 0, 0, 0);
        acc2[0][1] = __builtin_amdgcn_mfma_f32_16x16x32_bf16(w0, t1,  acc2[0][1], 0, 0, 0);
        acc2[0][2] = __builtin_amdgcn_mfma_f32_16x16x32_bf16(w0, t2,  acc2[0][2], 0, 0, 0);
        acc2[0][3] = __builtin_amdgcn_mfma_f32_16x16x32_bf16(w0, t3f, acc2[0][3], 0, 0, 0);
        acc2[1][0] = __builtin_amdgcn_mfma_f32_16x16x32_bf16(w1f, t0,  acc2[1][0], 0, 0, 0);
        acc2[1][1] = __builtin_amdgcn_mfma_f32_16x16x32_bf16(w1f, t1,  acc2[1][1], 0, 0, 0);
        acc2[1][2] = __builtin_amdgcn_mfma_f32_16x16x32_bf16(w1f, t2,  acc2[1][2], 0, 0, 0);
        acc2[1][3] = __builtin_amdgcn_mfma_f32_16x16x32_bf16(w1f, t3f, acc2[1][3], 0, 0, 0);
    }

    // ---- epilogue: +b2, direct float4 stores (4 consecutive cols per lane) ----
    const size_t rowbase = (size_t)blk * 64;
    #pragma unroll
    for (int mt = 0; mt < 2; mt++) {
        const float4 bv = mt ? b2v1 : b2v0;
        const int col = cbase + mt * 16 + quad * 4;
        #pragma unroll
        for (int nt = 0; nt < 4; nt++) {
            const size_t row = rowbase + nt * 16 + l16;
            float4 o;
            o.x = acc2[mt][nt][0] + bv.x;
            o.y = acc2[mt][nt][1] + bv.y;
            o.z = acc2[mt][nt][2] + bv.z;
            o.w = acc2[mt][nt][3] + bv.w;
            *(float4*)&out[row * 128 + col] = o;
        }
    }
}

// ---------------------------------------------------------------------------
extern "C" void kernel_launch(void* const* d_in, const int* in_sizes, int n_in,
                              void* d_out, int out_size, void* d_ws, size_t ws_size,
                              hipStream_t stream) {
    const float* s    = (const float*)d_in[0];
    const float* t3   = (const float*)d_in[1];
    const float* sc3  = (const float*)d_in[2];
    const float* pre  = (const float*)d_in[3];
    // d_in[4] = p_mask (all-ones, never applied in reference math)
    const float* W_sp = (const float*)d_in[5];
    const float* b_sp = (const float*)d_in[6];
    const float* W_rp = (const float*)d_in[7];
    const float* b_rp = (const float*)d_in[8];
    const float* W1   = (const float*)d_in[9];
    const float* b1   = (const float*)d_in[10];
    const float* W2   = (const float*)d_in[11];
    const float* b2   = (const float*)d_in[12];
    float* out = (float*)d_out;

    char* ws = (char*)d_ws;
    __hip_bfloat16* p_bf = (__hip_bfloat16*)(ws);                          // 64 KiB
    __hip_bfloat16* relT = (__hip_bfloat16*)(ws + 65536);                  // 128 KiB
    __hip_bfloat16* W1b  = (__hip_bfloat16*)(ws + 65536 + 131072);         // 64 KiB
    __hip_bfloat16* W2b  = (__hip_bfloat16*)(ws + 65536 + 131072 + 65536); // 32 KiB

    precompute_kernel<<<344, 256, 0, stream>>>(s, W_sp, b_sp, W_rp, b_rp, W1, W2,
                                               p_bf, relT, W1b, W2b);
    edge_main<<<4096, 256, 0, stream>>>(t3, sc3, pre, b1, b2,
                                        p_bf, relT, W1b, W2b, out);
}

// Round 4
// 200.600 us; speedup vs baseline: 1.1331x; 1.1331x over previous
//
#include <hip/hip_runtime.h>
#include <hip/hip_bf16.h>

// EdgeEmbedder fused kernel for MI355X (gfx950). Round 4: persistent blocks.
//   R3 post-mortem: occupancy 28->39% with zero speedup => structure-bound,
//   not occupancy-bound. Per-tile weight reloads (393MB L2) + serial phase
//   chain in 4096 short blocks pinned us at 85us.
//   This round: block = one i-row (grid 512, 2/CU), weights in VGPRs (once
//   per block), p_i segment folded into per-i bias (K 256->192, -25% MFMA),
//   double-buffered tile LDS (2x24KB + 16KB H = 64KB), stage t+1 loads into
//   registers during compute of t. 2 barriers/tile.

typedef __attribute__((ext_vector_type(8))) short v8s;   // 8 x bf16 fragment
typedef __attribute__((ext_vector_type(4))) float v4f;   // 4 x f32 accumulator

#define PI_F 3.14159265358979323846f

__device__ __forceinline__ unsigned short f2bu(float x) {
    __hip_bfloat16 h = __float2bfloat16(x);
    return *reinterpret_cast<unsigned short*>(&h);
}

// ---------------------------------------------------------------------------
// Precompute: blocks 0..63 -> p rows; 64..319 -> relpos rows; 320..343 ->
// W1/W2 bf16 cast. (unchanged, all global reads coalesced)
// ---------------------------------------------------------------------------
__global__ __launch_bounds__(256) void precompute_kernel(
    const float* __restrict__ s, const float* __restrict__ W_sp,
    const float* __restrict__ b_sp, const float* __restrict__ W_rp,
    const float* __restrict__ b_rp, const float* __restrict__ W1,
    const float* __restrict__ W2,
    __hip_bfloat16* __restrict__ p_bf, __hip_bfloat16* __restrict__ relT,
    __hip_bfloat16* __restrict__ W1b, __hip_bfloat16* __restrict__ W2b)
{
    const int b = blockIdx.x;
    const int tid = threadIdx.x;
    __shared__ float lds[128 * 65 + 8 * 256];

    if (b < 64) {
        float* Wt   = lds;               // [128][65] transposed slice of W_sp
        float* srow = lds + 128 * 65;    // [8][256]
        const int row0 = b * 8;
        const int f  = tid & 63;
        const int rh = tid >> 6;
        #pragma unroll
        for (int k = 0; k < 8; k++) {
            const int idx = tid + 256 * k;
            const int r = idx >> 8, d = idx & 255;
            srow[r * 256 + d] = s[(row0 + r) * 256 + d];
        }
        float acc0 = b_sp[f];
        float acc1 = acc0;
        for (int pass = 0; pass < 2; pass++) {
            __syncthreads();
            #pragma unroll
            for (int k = 0; k < 32; k++) {
                const int idx = tid + 256 * k;
                const int fs = idx >> 7, ds = idx & 127;
                Wt[ds * 65 + fs] = W_sp[fs * 256 + pass * 128 + ds];
            }
            __syncthreads();
            #pragma unroll 4
            for (int d = 0; d < 128; d++) {
                const float w = Wt[d * 65 + f];
                acc0 += srow[rh * 256 + pass * 128 + d] * w;
                acc1 += srow[(rh + 4) * 256 + pass * 128 + d] * w;
            }
        }
        p_bf[(row0 + rh) * 64 + f]     = __float2bfloat16(acc0);
        p_bf[(row0 + rh + 4) * 64 + f] = __float2bfloat16(acc1);
    } else if (b < 320) {
        float* WrT  = lds;               // [64][65] transposed W_rp
        float* femb = lds + 64 * 65;     // [4][64]
        const int r0 = (b - 64) * 4;
        #pragma unroll
        for (int k = 0; k < 16; k++) {
            const int idx = tid + 256 * k;
            const int g = idx >> 6, ff = idx & 63;
            WrT[ff * 65 + g] = W_rp[g * 64 + ff];
        }
        {
            const int r = tid >> 6, c = tid & 63;
            const float rel = (float)(r0 + r - 511);
            const int K = c & 31;
            const float freq = powf(2056.0f, (2.0f * (float)K) / 64.0f);
            const float ang = rel * PI_F / freq;
            femb[r * 64 + c] = (c < 32) ? sinf(ang) : cosf(ang);
        }
        __syncthreads();
        const int g = tid & 63, r = tid >> 6;
        float acc = b_rp[g];
        #pragma unroll
        for (int ff = 0; ff < 64; ff++) acc += femb[r * 64 + ff] * WrT[ff * 65 + g];
        relT[(r0 + r) * 64 + g] = __float2bfloat16(acc);
    } else {
        #pragma unroll
        for (int k = 0; k < 2; k++) {
            const int idx4 = (b - 320) * 512 + k * 256 + tid;
            const int e = idx4 * 4;
            const float4 v = (e < 32768) ? *(const float4*)&W1[e]
                                         : *(const float4*)&W2[e - 32768];
            __hip_bfloat16* dst = (e < 32768) ? (W1b + e) : (W2b + (e - 32768));
            dst[0] = __float2bfloat16(v.x);
            dst[1] = __float2bfloat16(v.y);
            dst[2] = __float2bfloat16(v.z);
            dst[3] = __float2bfloat16(v.w);
        }
    }
}

// ---------------------------------------------------------------------------
// bias1[i][c] = b1[c] + sum_{f<64} p[i][f] * W1[c][f]   (p_i segment folded)
// ---------------------------------------------------------------------------
__global__ __launch_bounds__(128) void bias1_kernel(
    const __hip_bfloat16* __restrict__ p_bf, const __hip_bfloat16* __restrict__ W1b,
    const float* __restrict__ b1, float* __restrict__ bias1)
{
    const int i = blockIdx.x;       // 512
    const int c = threadIdx.x;      // 128
    __shared__ float prow[64];
    if (c < 64) prow[c] = __bfloat162float(p_bf[i * 64 + c]);
    __syncthreads();
    float acc = b1[c];
    const __hip_bfloat16* w = W1b + c * 256;
    #pragma unroll 8
    for (int f = 0; f < 64; f++) acc += prow[f] * __bfloat162float(w[f]);
    bias1[i * 128 + c] = acc;
}

// ---------------------------------------------------------------------------
// Main persistent kernel. Block = one i (512 blocks, 2/CU), 8 j-tiles of 64.
// Wave wv owns output cols [32wv, 32wv+32). A=weight frag (regs), B=tile frag.
// Tile K=192: [0,64) p_j | [64,128) relpos | [128,172) RBF | [172,192) pre.
// LDS 65536B: T0 @0 (24576 = 64x384), T1 @24576, H @49152 (16384 = 64x256).
// Swizzle: 16B chunk c of row r stored at chunk (c ^ (r&7)) (low 3 bits).
// ---------------------------------------------------------------------------
__global__ __launch_bounds__(256, 2) void edge_main(
    const float* __restrict__ t3, const float* __restrict__ sc3,
    const float* __restrict__ pre, const float* __restrict__ bias1,
    const float* __restrict__ b2,
    const __hip_bfloat16* __restrict__ p_bf, const __hip_bfloat16* __restrict__ relT,
    const __hip_bfloat16* __restrict__ W1b, const __hip_bfloat16* __restrict__ W2b,
    float* __restrict__ out)
{
    __shared__ char smem[65536];

    const int tid  = threadIdx.x;
    const int i    = blockIdx.x;
    const int wv   = tid >> 6;
    const int lane = tid & 63;
    const int l16  = lane & 15;
    const int quad = lane >> 4;
    const int cbase = wv * 32;
    const int rx16 = l16 & 7;

    // ---- weights -> registers (once per block) ----
    v8s w1f[2][6];
    v8s w2f[2][4];
    {
        const __hip_bfloat16* a = W1b + (cbase + l16) * 256 + 64 + quad * 8;
        #pragma unroll
        for (int mt = 0; mt < 2; mt++)
            #pragma unroll
            for (int kt = 0; kt < 6; kt++)
                w1f[mt][kt] = *(const v8s*)(a + mt * 16 * 256 + kt * 32);
        const __hip_bfloat16* a2 = W2b + (cbase + l16) * 128 + quad * 8;
        #pragma unroll
        for (int mt = 0; mt < 2; mt++)
            #pragma unroll
            for (int kt = 0; kt < 4; kt++)
                w2f[mt][kt] = *(const v8s*)(a2 + mt * 16 * 128 + kt * 32);
    }
    const float4 bz0 = *(const float4*)&b2[cbase + quad * 4];
    const float4 bz1 = *(const float4*)&b2[cbase + 16 + quad * 4];
    const float4 bo0 = *(const float4*)&bias1[i * 128 + cbase + quad * 4];
    const float4 bo1 = *(const float4*)&bias1[i * 128 + cbase + 16 + quad * 4];

    const float tix = t3[i * 3], tiy = t3[i * 3 + 1], tiz = t3[i * 3 + 2];
    const float six = sc3[i * 3], siy = sc3[i * 3 + 1], siz = sc3[i * 3 + 2];

    // staging slot indices (fixed per thread)
    const int rA = tid >> 3, ckA = tid & 7;        // p_j/rel slot A (rows 0..31)
    const int rB = rA + 32;                        // slot B (rows 32..63)
    const int rp0 = tid / 5, qp0 = tid % 5;        // pre slot 0
    const int rp1 = (tid + 256) / 5, qp1 = (tid + 256) % 5;  // pre slot 1 (tid<64)
    const int rr = tid >> 2, fo = (tid & 3) * 11;  // rbf row, feature base

    uint4 s_pjA, s_pjB, s_rlA, s_rlB;
    float4 s_prA, s_prB;
    float s_dt, s_ds;

    auto stage = [&](int j0n) {
        s_pjA = *(const uint4*)&p_bf[(j0n + rA) * 64 + ckA * 8];
        s_pjB = *(const uint4*)&p_bf[(j0n + rB) * 64 + ckA * 8];
        s_rlA = *(const uint4*)&relT[(i - (j0n + rA) + 511) * 64 + ckA * 8];
        s_rlB = *(const uint4*)&relT[(i - (j0n + rB) + 511) * 64 + ckA * 8];
        s_prA = *(const float4*)&pre[((size_t)i * 512 + j0n + rp0) * 20 + qp0 * 4];
        if (tid < 64)
            s_prB = *(const float4*)&pre[((size_t)i * 512 + j0n + rp1) * 20 + qp1 * 4];
        const int j = j0n + rr;
        const float dx = tix - t3[j * 3], dy = tiy - t3[j * 3 + 1], dz = tiz - t3[j * 3 + 2];
        s_dt = sqrtf(dx * dx + dy * dy + dz * dz);
        const float ex = six - sc3[j * 3], ey = siy - sc3[j * 3 + 1], ez = siz - sc3[j * 3 + 2];
        s_ds = sqrtf(ex * ex + ey * ey + ez * ez);
    };

    auto build = [&](char* T) {
        {   // p_j (chunks 0..7) + rel (chunks 8..15)
            const int xA = (ckA ^ (rA & 7)) << 4;
            *(uint4*)(T + rA * 384 + xA)       = s_pjA;
            *(uint4*)(T + rA * 384 + 128 + xA) = s_rlA;
            const int xB = (ckA ^ (rB & 7)) << 4;
            *(uint4*)(T + rB * 384 + xB)       = s_pjB;
            *(uint4*)(T + rB * 384 + 128 + xB) = s_rlB;
        }
        {   // pre -> cols 172..191 (sub = 44 + q*4 within Q segment)
            union { unsigned short u2[4]; uint2 u; } pk;
            const int sub0 = 44 + qp0 * 4;
            pk.u2[0] = f2bu(s_prA.x); pk.u2[1] = f2bu(s_prA.y);
            pk.u2[2] = f2bu(s_prA.z); pk.u2[3] = f2bu(s_prA.w);
            *(uint2*)(T + rp0 * 384 + 256 + (((sub0 >> 3) ^ (rp0 & 7)) << 4) + (sub0 & 7) * 2) = pk.u;
            if (tid < 64) {
                const int sub1 = 44 + qp1 * 4;
                pk.u2[0] = f2bu(s_prB.x); pk.u2[1] = f2bu(s_prB.y);
                pk.u2[2] = f2bu(s_prB.z); pk.u2[3] = f2bu(s_prB.w);
                *(uint2*)(T + rp1 * 384 + 256 + (((sub1 >> 3) ^ (rp1 & 7)) << 4) + (sub1 & 7) * 2) = pk.u;
            }
        }
        {   // RBF -> cols 128..171 (sub = f within Q segment)
            const int rxr = rr & 7;
            char* rowp = T + rr * 384 + 256;
            #pragma unroll
            for (int q = 0; q < 11; q++) {
                const int f = fo + q;
                const float d = (f < 22) ? s_dt : s_ds;
                const int m = (f < 22) ? f : f - 22;
                const float x = (d - (float)m * (20.0f / 21.0f)) * 1.1f;
                *(unsigned short*)(rowp + (((f >> 3) ^ rxr) << 4) + (f & 7) * 2)
                    = f2bu(__expf(-x * x));
            }
        }
    };

    // ---- prologue: build tile 0 ----
    stage(0);
    build(smem);
    __syncthreads();

    char* Hb = smem + 49152;
    const size_t orow0 = (size_t)i * 512;

    #pragma unroll 1
    for (int s = 0; s < 8; s++) {
        char* T  = smem + ((s & 1) ? 24576 : 0);
        char* Tn = smem + ((s & 1) ? 0 : 24576);
        if (s < 7) stage((s + 1) * 64);   // loads in flight during compute

        // ---- Layer 1: K=192, weights in regs ----
        v4f acc[2][4];
        #pragma unroll
        for (int mt = 0; mt < 2; mt++)
            #pragma unroll
            for (int nt = 0; nt < 4; nt++) acc[mt][nt] = (v4f){0.f, 0.f, 0.f, 0.f};

        #pragma unroll
        for (int kt = 0; kt < 6; kt++) {
            const int g = kt * 4 + quad;
            const int po = ((g ^ rx16) << 4);    // XOR affects low-3 chunk bits only
            const v8s t0 = *(const v8s*)(T + (l16     ) * 384 + po);
            const v8s t1 = *(const v8s*)(T + (l16 + 16) * 384 + po);
            const v8s t2 = *(const v8s*)(T + (l16 + 32) * 384 + po);
            const v8s t3v = *(const v8s*)(T + (l16 + 48) * 384 + po);
            acc[0][0] = __builtin_amdgcn_mfma_f32_16x16x32_bf16(w1f[0][kt], t0,  acc[0][0], 0, 0, 0);
            acc[0][1] = __builtin_amdgcn_mfma_f32_16x16x32_bf16(w1f[0][kt], t1,  acc[0][1], 0, 0, 0);
            acc[0][2] = __builtin_amdgcn_mfma_f32_16x16x32_bf16(w1f[0][kt], t2,  acc[0][2], 0, 0, 0);
            acc[0][3] = __builtin_amdgcn_mfma_f32_16x16x32_bf16(w1f[0][kt], t3v, acc[0][3], 0, 0, 0);
            acc[1][0] = __builtin_amdgcn_mfma_f32_16x16x32_bf16(w1f[1][kt], t0,  acc[1][0], 0, 0, 0);
            acc[1][1] = __builtin_amdgcn_mfma_f32_16x16x32_bf16(w1f[1][kt], t1,  acc[1][1], 0, 0, 0);
            acc[1][2] = __builtin_amdgcn_mfma_f32_16x16x32_bf16(w1f[1][kt], t2,  acc[1][2], 0, 0, 0);
            acc[1][3] = __builtin_amdgcn_mfma_f32_16x16x32_bf16(w1f[1][kt], t3v, acc[1][3], 0, 0, 0);
        }

        // ---- H = relu(acc + bias1_i) -> H plane ----
        #pragma unroll
        for (int mt = 0; mt < 2; mt++) {
            const float4 bv = mt ? bo1 : bo0;
            const int col = cbase + mt * 16 + quad * 4;
            const int cch = col >> 3;
            const int boff = (col & 7) * 2;
            #pragma unroll
            for (int nt = 0; nt < 4; nt++) {
                const int row = nt * 16 + l16;
                union { unsigned short u2[4]; uint2 u; } pk;
                pk.u2[0] = f2bu(fmaxf(acc[mt][nt][0] + bv.x, 0.f));
                pk.u2[1] = f2bu(fmaxf(acc[mt][nt][1] + bv.y, 0.f));
                pk.u2[2] = f2bu(fmaxf(acc[mt][nt][2] + bv.z, 0.f));
                pk.u2[3] = f2bu(fmaxf(acc[mt][nt][3] + bv.w, 0.f));
                *(uint2*)(Hb + row * 256 + ((cch ^ (row & 7)) << 4) + boff) = pk.u;
            }
        }
        __syncthreads();   // H complete (and T reads done — T rebuilt only next iter)

        // ---- Layer 2: K=128 from H ----
        v4f acc2[2][4];
        #pragma unroll
        for (int mt = 0; mt < 2; mt++)
            #pragma unroll
            for (int nt = 0; nt < 4; nt++) acc2[mt][nt] = (v4f){0.f, 0.f, 0.f, 0.f};

        #pragma unroll
        for (int kt = 0; kt < 4; kt++) {
            const int g = kt * 4 + quad;
            const int po = ((g ^ rx16) << 4);
            const v8s t0 = *(const v8s*)(Hb + (l16     ) * 256 + po);
            const v8s t1 = *(const v8s*)(Hb + (l16 + 16) * 256 + po);
            const v8s t2 = *(const v8s*)(Hb + (l16 + 32) * 256 + po);
            const v8s t3v = *(const v8s*)(Hb + (l16 + 48) * 256 + po);
            acc2[0][0] = __builtin_amdgcn_mfma_f32_16x16x32_bf16(w2f[0][kt], t0,  acc2[0][0], 0, 0, 0);
            acc2[0][1] = __builtin_amdgcn_mfma_f32_16x16x32_bf16(w2f[0][kt], t1,  acc2[0][1], 0, 0, 0);
            acc2[0][2] = __builtin_amdgcn_mfma_f32_16x16x32_bf16(w2f[0][kt], t2,  acc2[0][2], 0, 0, 0);
            acc2[0][3] = __builtin_amdgcn_mfma_f32_16x16x32_bf16(w2f[0][kt], t3v, acc2[0][3], 0, 0, 0);
            acc2[1][0] = __builtin_amdgcn_mfma_f32_16x16x32_bf16(w2f[1][kt], t0,  acc2[1][0], 0, 0, 0);
            acc2[1][1] = __builtin_amdgcn_mfma_f32_16x16x32_bf16(w2f[1][kt], t1,  acc2[1][1], 0, 0, 0);
            acc2[1][2] = __builtin_amdgcn_mfma_f32_16x16x32_bf16(w2f[1][kt], t2,  acc2[1][2], 0, 0, 0);
            acc2[1][3] = __builtin_amdgcn_mfma_f32_16x16x32_bf16(w2f[1][kt], t3v, acc2[1][3], 0, 0, 0);
        }

        // ---- epilogue: +b2, direct float4 stores ----
        #pragma unroll
        for (int mt = 0; mt < 2; mt++) {
            const float4 bv = mt ? bz1 : bz0;
            const int col = cbase + mt * 16 + quad * 4;
            #pragma unroll
            for (int nt = 0; nt < 4; nt++) {
                const size_t row = orow0 + s * 64 + nt * 16 + l16;
                float4 o;
                o.x = acc2[mt][nt][0] + bv.x;
                o.y = acc2[mt][nt][1] + bv.y;
                o.z = acc2[mt][nt][2] + bv.z;
                o.w = acc2[mt][nt][3] + bv.w;
                *(float4*)&out[row * 128 + col] = o;
            }
        }

        if (s < 7) build(Tn);   // convert staged regs -> next tile LDS
        __syncthreads();        // Tn ready; H reads done before next overwrite
    }
}

// ---------------------------------------------------------------------------
extern "C" void kernel_launch(void* const* d_in, const int* in_sizes, int n_in,
                              void* d_out, int out_size, void* d_ws, size_t ws_size,
                              hipStream_t stream) {
    const float* s    = (const float*)d_in[0];
    const float* t3   = (const float*)d_in[1];
    const float* sc3  = (const float*)d_in[2];
    const float* pre  = (const float*)d_in[3];
    // d_in[4] = p_mask (all-ones, never applied in reference math)
    const float* W_sp = (const float*)d_in[5];
    const float* b_sp = (const float*)d_in[6];
    const float* W_rp = (const float*)d_in[7];
    const float* b_rp = (const float*)d_in[8];
    const float* W1   = (const float*)d_in[9];
    const float* b1   = (const float*)d_in[10];
    const float* W2   = (const float*)d_in[11];
    const float* b2   = (const float*)d_in[12];
    float* out = (float*)d_out;

    char* ws = (char*)d_ws;
    __hip_bfloat16* p_bf = (__hip_bfloat16*)(ws);                   // 64 KiB @0
    __hip_bfloat16* relT = (__hip_bfloat16*)(ws + 65536);           // 128 KiB
    __hip_bfloat16* W1b  = (__hip_bfloat16*)(ws + 196608);          // 64 KiB
    __hip_bfloat16* W2b  = (__hip_bfloat16*)(ws + 262144);          // 32 KiB
    float*          bias1 = (float*)(ws + 294912);                  // 256 KiB

    precompute_kernel<<<344, 256, 0, stream>>>(s, W_sp, b_sp, W_rp, b_rp, W1, W2,
                                               p_bf, relT, W1b, W2b);
    bias1_kernel<<<512, 128, 0, stream>>>(p_bf, W1b, b1, bias1);
    edge_main<<<512, 256, 0, stream>>>(t3, sc3, pre, bias1, b2,
                                       p_bf, relT, W1b, W2b, out);
}